// Round 3
// baseline (470.863 us; speedup 1.0000x reference)
//
#include <hip/hip_runtime.h>

typedef __attribute__((ext_vector_type(4))) short bf16x4;
typedef __attribute__((ext_vector_type(8))) short bf16x8;
typedef __attribute__((ext_vector_type(16))) float f32x16;
typedef __attribute__((ext_vector_type(4))) float f32x4;

typedef __attribute__((address_space(3))) unsigned int lds_u32_t;
typedef const __attribute__((address_space(1))) unsigned int glb_u32_t;

__device__ __forceinline__ unsigned short f2bf(float f) {
    unsigned int u = __builtin_bit_cast(unsigned int, f);
    u += 0x7fffu + ((u >> 16) & 1u);   // RNE (finite normals only)
    return (unsigned short)(u >> 16);
}

#define PA2 60   // A-strip pitch in shorts: 120 B/row -> 30 dwords, 2-way bank alias (free), 8B aligned

// K reordered into 16 strips of 48 vk: strip = slab*4 + j, slab=(i,chunk), j=p-quarter.
// Strip-local vk = c3*16 + pl16, pl = 16j + pl16 (pl>=60 is pad: A zeroed, W skipped).
__global__ __launch_bounds__(1024) void gemm_kernel(
    const float* __restrict__ x,
    const float* __restrict__ rw, const float* __restrict__ sw, const float* __restrict__ cw,
    const float* __restrict__ W,
    const float* __restrict__ Rr, const float* __restrict__ Rs, const float* __restrict__ Rc,
    float* __restrict__ P)
{
    __shared__ unsigned short lds_a[2][256 * PA2];  // 2 x 30720 B  bf16 feats [n][48vk]
    __shared__ float          lds_b[2][48 * 256];   // 2 x 49152 B  raw fp32 W   [48vk][256d]

    const int tid  = threadIdx.x;
    const int blk  = blockIdx.x;
    const int p0   = blk * 60;
    const int lane = tid & 63, wv = tid >> 6;
    const int lm   = lane & 31, lh = lane >> 5;
    const int m0   = (wv >> 2) * 64;   // wave-tile 64x64
    const int d0   = (wv & 3) * 64;
    const int xn   = tid >> 2;         // A-staging: n (0..255)
    const int xp4  = tid & 3;          // A-staging: 4-float p group within 16-p strip

    // ---- Rtot = (R_rotate*rw) @ (R_shear*sw) @ (R_scale*cw), row-major [c][d] ----
    float Ar[9], Br[9], Cr[9], T1[9], RT[9];
    #pragma unroll
    for (int e = 0; e < 9; ++e) { Ar[e] = Rr[e]*rw[e]; Br[e] = Rs[e]*sw[e]; Cr[e] = Rc[e]*cw[e]; }
    #pragma unroll
    for (int r = 0; r < 3; ++r)
        #pragma unroll
        for (int c = 0; c < 3; ++c)
            T1[r*3+c] = Ar[r*3+0]*Br[0*3+c] + Ar[r*3+1]*Br[1*3+c] + Ar[r*3+2]*Br[2*3+c];
    #pragma unroll
    for (int r = 0; r < 3; ++r)
        #pragma unroll
        for (int c = 0; c < 3; ++c)
            RT[r*3+c] = T1[r*3+0]*Cr[0*3+c] + T1[r*3+1]*Cr[1*3+c] + T1[r*3+2]*Cr[2*3+c];

    f32x16 acc[2][2];
    #pragma unroll
    for (int fm = 0; fm < 2; ++fm)
        #pragma unroll
        for (int fd = 0; fd < 2; ++fd)
            acc[fm][fd] = (f32x16)0.0f;

    f32x4 X0 = (f32x4)0.f, X1 = (f32x4)0.f, X2 = (f32x4)0.f;

    // issue prefetch (W->LDS DMA + x->regs) for strip ns
    auto issue = [&](int ns) {
        const int s2 = ns >> 2, j2 = ns & 3;
        const long kb2 = (long)(s2 >> 1) * 90000 + (long)(s2 & 1) * 45000 + p0;
        // W DMA: wave wv owns rows (q*16 + wv), q=0..2; 1 row = 1KB = one width-16 wave op
        const int pl = j2 * 16 + wv;
        if (pl < 60) {
            #pragma unroll
            for (int q = 0; q < 3; ++q) {
                glb_u32_t* g = (glb_u32_t*)(W + (kb2 + (long)q * 15000 + pl) * 256 + lane * 4);
                lds_u32_t* l = (lds_u32_t*)&lds_b[ns & 1][(q * 16 + wv) * 256];
                __builtin_amdgcn_global_load_lds(g, l, 16, 0, 0);
            }
        }
        // x: thread owns (n=xn, p4=xp4): 3 c'-rows of 4 floats
        const bool ok = !(j2 == 3 && xp4 == 3);   // pl 60..63 pad (also avoids OOB)
        const float* px = x + kb2 + (long)xn * 180000 + j2 * 16 + xp4 * 4;
        X0 = ok ? *(const f32x4*)px           : (f32x4)0.f;
        X1 = ok ? *(const f32x4*)(px + 15000) : (f32x4)0.f;
        X2 = ok ? *(const f32x4*)(px + 30000) : (f32x4)0.f;
    };

    // convert x regs -> bf16 A-strip ns
    auto convertA = [&](int ns) {
        bf16x4 o0, o1, o2;
        #pragma unroll
        for (int e = 0; e < 4; ++e) {
            float x0 = X0[e], x1 = X1[e], x2 = X2[e];
            o0[e] = (short)f2bf(x0*RT[0] + x1*RT[3] + x2*RT[6]);
            o1[e] = (short)f2bf(x0*RT[1] + x1*RT[4] + x2*RT[7]);
            o2[e] = (short)f2bf(x0*RT[2] + x1*RT[5] + x2*RT[8]);
        }
        const int a = xn * PA2 + xp4 * 4;
        unsigned short* dst = &lds_a[ns & 1][0];
        *(bf16x4*)&dst[a     ] = o0;   // c3=0
        *(bf16x4*)&dst[a + 16] = o1;   // c3=1
        *(bf16x4*)&dst[a + 32] = o2;   // c3=2
    };

    // ---- prologue: stage strip 0 ----
    issue(0);
    convertA(0);
    __syncthreads();

    // ---- 16-strip pipelined main loop ----
    for (int strip = 0; strip < 16; ++strip) {
        const int cur = strip & 1;
        const int ns  = strip + 1;
        if (ns < 16) issue(ns);

        const unsigned short* Ab = &lds_a[cur][0];
        const float*          Bb = &lds_b[cur][0];
        #pragma unroll
        for (int kk = 0; kk < 3; ++kk) {
            const int kb = kk * 16 + lh * 8;
            bf16x8 af[2];
            #pragma unroll
            for (int fm = 0; fm < 2; ++fm) {
                const unsigned short* pa = &Ab[(m0 + fm * 32 + lm) * PA2 + kb];
                bf16x4 alo = *(const bf16x4*)pa;
                bf16x4 ahi = *(const bf16x4*)(pa + 4);
                af[fm] = __builtin_shufflevector(alo, ahi, 0,1,2,3,4,5,6,7);
            }
            #pragma unroll
            for (int fd = 0; fd < 2; ++fd) {
                const int db = d0 + fd * 32 + lm;
                float bv[8];
                #pragma unroll
                for (int jj = 0; jj < 8; ++jj) bv[jj] = Bb[(kb + jj) * 256 + db];
                bf16x8 bfv;
                #pragma unroll
                for (int jj = 0; jj < 8; ++jj) bfv[jj] = (short)f2bf(bv[jj]);
                #pragma unroll
                for (int fm = 0; fm < 2; ++fm)
                    acc[fm][fd] = __builtin_amdgcn_mfma_f32_32x32x16_bf16(af[fm], bfv, acc[fm][fd], 0, 0, 0);
            }
        }

        if (ns < 16) convertA(ns);
        __syncthreads();
    }

    // ---- epilogue: P[n][s][d] so the reduce streams contiguously ----
    #pragma unroll
    for (int fm = 0; fm < 2; ++fm)
        #pragma unroll
        for (int fd = 0; fd < 2; ++fd)
            #pragma unroll
            for (int r = 0; r < 16; ++r) {
                int row = m0 + fm * 32 + (r & 3) + 8 * (r >> 2) + 4 * lh;
                int col = d0 + fd * 32 + lm;
                P[((size_t)row * 250 + blk) * 256 + col] = acc[fm][fd][r];
            }
}

// Sum 250 partials (contiguous per n) + bias -> z (twice to out), zhat -> Z.
__global__ __launch_bounds__(256) void reduce_kernel(
    const float* __restrict__ P, const float* __restrict__ bias,
    float* __restrict__ out, float* __restrict__ Z)
{
    __shared__ f32x4 sred[4][64];
    const int n = blockIdx.x;
    const int tid = threadIdx.x;
    const int d4 = tid & 63, sg = tid >> 6;

    const f32x4* base = (const f32x4*)(P + (size_t)n * 250 * 256);
    f32x4 z = (f32x4)0.f;
    for (int s = sg; s < 250; s += 4) z += base[s * 64 + d4];
    sred[sg][d4] = z;
    __syncthreads();

    if (tid < 64) {
        f32x4 zf = sred[0][tid] + sred[1][tid] + sred[2][tid] + sred[3][tid];
        zf += ((const f32x4*)bias)[tid];
        float* o1 = out + 1 + n * 256 + tid * 4;   // out+1: 4B-aligned only
        float* o2 = o1 + 65536;
        #pragma unroll
        for (int e = 0; e < 4; ++e) { o1[e] = zf[e]; o2[e] = zf[e]; }
        float sq = zf[0]*zf[0] + zf[1]*zf[1] + zf[2]*zf[2] + zf[3]*zf[3];
        #pragma unroll
        for (int off = 32; off > 0; off >>= 1) sq += __shfl_xor(sq, off, 64);
        float inv = rsqrtf(sq);
        ((f32x4*)Z)[n * 64 + tid] = zf * inv;
    }
}

// loss = 2 - (2/255)*(||S||^2/256 - 1), S = sum_n zhat_n
__global__ __launch_bounds__(1024) void loss_kernel(const float* __restrict__ Z, float* __restrict__ out)
{
    __shared__ f32x4 sp[16][64];
    const int tid = threadIdx.x;
    const int c4 = tid & 63, g = tid >> 6;
    f32x4 S = (f32x4)0.f;
    #pragma unroll 4
    for (int n = g; n < 256; n += 16) S += ((const f32x4*)Z)[n * 64 + c4];
    sp[g][c4] = S;
    __syncthreads();
    if (tid < 64) {
        f32x4 T = sp[0][tid];
        #pragma unroll
        for (int gg = 1; gg < 16; ++gg) T += sp[gg][tid];
        float v = T[0]*T[0] + T[1]*T[1] + T[2]*T[2] + T[3]*T[3];
        #pragma unroll
        for (int off = 32; off > 0; off >>= 1) v += __shfl_xor(v, off, 64);
        if (tid == 0)
            out[0] = 2.0f - (2.0f / 255.0f) * (v * (1.0f / 256.0f) - 1.0f);
    }
}

extern "C" void kernel_launch(void* const* d_in, const int* in_sizes, int n_in,
                              void* d_out, int out_size, void* d_ws, size_t ws_size,
                              hipStream_t stream)
{
    (void)in_sizes; (void)n_in; (void)out_size; (void)ws_size;
    const float* x  = (const float*)d_in[0];
    const float* rw = (const float*)d_in[1];
    const float* sw = (const float*)d_in[2];
    const float* cw = (const float*)d_in[3];
    const float* W  = (const float*)d_in[4];
    const float* bb = (const float*)d_in[5];
    const float* Rr = (const float*)d_in[6];
    const float* Rs = (const float*)d_in[7];
    const float* Rc = (const float*)d_in[8];
    float* out = (float*)d_out;
    float* P = (float*)d_ws;                        // 256n x 250s x 256d fp32 partials
    float* Z = P + (size_t)256 * 250 * 256;         // 65536 fp32 zhat

    gemm_kernel<<<250, 1024, 0, stream>>>(x, rw, sw, cw, W, Rr, Rs, Rc, P);
    reduce_kernel<<<256, 256, 0, stream>>>(P, bb, out, Z);
    loss_kernel<<<1, 1024, 0, stream>>>(Z, out);
}